// Round 1
// baseline (202.259 us; speedup 1.0000x reference)
//
#include <hip/hip_runtime.h>

// Problem constants (fixed by setup_inputs)
#define U    128
#define TN   (256 * 1024)         // T*N output elements
#define TN4  (TN / 4)             // float4 granularity (65536)
#define NBLK 256                  // blocks (= TN4 / 256): 1 block/CU, 4 waves/CU
#define PF   16                   // uo float4s prefetched before the w barrier

// Native clang vector type — accepted by __builtin_nontemporal_load/store
typedef float vfloat4 __attribute__((ext_vector_type(4)));

// ws layout (floats): [0..255] per-block sum(final), [256..511] per-block sum(insp),
// [512] = ticket counter (memset to 0 in kernel_launch each replay; ws is poisoned).
// Single kernel: last-block-ticket pattern replaces the second dispatch.

__global__ __launch_bounds__(256, 1) void fused_kernel(const float*   __restrict__ conn,
                                                       const vfloat4* __restrict__ uo,
                                                       const vfloat4* __restrict__ tgt,
                                                       const vfloat4* __restrict__ insp,
                                                       const vfloat4* __restrict__ rb,
                                                       vfloat4*       __restrict__ out,
                                                       float*         __restrict__ ws,
                                                       unsigned int*  __restrict__ ticket) {
    __shared__ float wpart[2][U];
    __shared__ float w_s[U];
    __shared__ float red[8];
    __shared__ int   is_last_s;
    int tid = threadIdx.x;
    int idx = blockIdx.x * 256 + tid;            // 0..TN4-1

    // Early epilogue loads — latency overlapped with the w[] compute.
    vfloat4 t  = tgt[idx];
    vfloat4 is = insp[idx];

    // Start the 134 MB HBM stream BEFORE the w barriers: 16 float4s held in regs.
    // (Loads can't be hoisted past __syncthreads by the compiler, so do it manually.)
    const vfloat4* p = uo + idx;
    vfloat4 pre[PF];
#pragma unroll
    for (int k = 0; k < PF; ++k)
        pre[k] = __builtin_nontemporal_load(p + (size_t)k * TN4);

    // --- w[j] = 1.5 * sum_i gated(conn[i][j])   (3.0 [strength] * 0.5 [epilogue] folded)
    // Redundant per block; 64 KB from L2, overlaps the in-flight uo prefetch.
    {
        int j = tid & 127;
        int h = tid >> 7;
        const float* cp = conn + (size_t)(h * 64) * U + j;
        float s = 0.0f;
#pragma unroll
        for (int k = 0; k < 64; ++k) {
            float v = cp[(size_t)k * U];         // consecutive j -> coalesced
            s += (v > 0.1f) ? v : 0.0f;
        }
        wpart[h][j] = s;
    }
    __syncthreads();
    if (tid < U) w_s[tid] = 1.5f * (wpart[0][tid] + wpart[1][tid]);
    __syncthreads();

    // --- weighted j-reduction: consume prefetch, then stream with 16 in flight.
    vfloat4 acc = 0.0f;
#pragma unroll
    for (int k = 0; k < PF; ++k)
        acc += w_s[k] * pre[k];
#pragma unroll 16
    for (int jj = PF; jj < U; ++jj)              // 112 iters = 7 groups of 16
        acc += w_s[jj] * __builtin_nontemporal_load(p + (size_t)jj * TN4);

    vfloat4 r = acc + 1.5f * t;                  // 0.5*sum already folded into w_s
    __builtin_nontemporal_store(r, out + idx);   // written once; keep L2 clean

    // --- per-block partial sums: sum(final), sum(input_spikes)
    float lsum = r.x + r.y + r.z + r.w;
    float lin  = is.x + is.y + is.z + is.w;
#pragma unroll
    for (int off = 32; off > 0; off >>= 1) {
        lsum += __shfl_down(lsum, off, 64);
        lin  += __shfl_down(lin,  off, 64);
    }
    int wave = tid >> 6;
    int lane = tid & 63;
    if (lane == 0) { red[wave] = lsum; red[4 + wave] = lin; }
    __syncthreads();                             // also drains the out stores (vmcnt(0) before barrier)
    if (tid == 0) {
        ws[blockIdx.x]        = red[0] + red[1] + red[2] + red[3];
        ws[NBLK + blockIdx.x] = red[4] + red[5] + red[6] + red[7];
        __threadfence();                         // release: partials + out visible device-wide
        unsigned int prev = atomicAdd(ticket, 1u);   // device scope by default
        is_last_s = (prev == NBLK - 1);
    }
    __syncthreads();
    if (!is_last_s) return;

    // --- last block: grid-wide reduce + conditional boost (dead for this data).
    __threadfence();                             // acquire: see all blocks' partials
    float a = ws[tid];                           // 256 partials, one per thread
    float b = ws[NBLK + tid];
#pragma unroll
    for (int off = 32; off > 0; off >>= 1) {
        a += __shfl_down(a, off, 64);
        b += __shfl_down(b, off, 64);
    }
    if (lane == 0) { red[wave] = a; red[4 + wave] = b; }
    __syncthreads();
    float tot = red[0] + red[1] + red[2] + red[3];
    float tin = red[4] + red[5] + red[6] + red[7];

    float mean        = tot * (1.0f / TN);
    float in_rate     = tin * (1000.0f / TN);    // input_spikes.mean() * 1000
    float target_mean = (in_rate + 20.0f) * 0.01f;
    float boost       = fmaxf(0.0f, target_mean - mean);
    if (mean < 0.2f) {                           // never taken here (mean ~6e3); correct if taken
        float s2 = boost * 2.0f;
        for (int i = tid; i < TN4; i += 256) {
            vfloat4 o = out[i];
            out[i] = o + rb[i] * s2;
        }
    }
}

extern "C" void kernel_launch(void* const* d_in, const int* in_sizes, int n_in,
                              void* d_out, int out_size, void* d_ws, size_t ws_size,
                              hipStream_t stream) {
    const float* input_spikes = (const float*)d_in[0];   // [T,N]
    const float* unit_outputs = (const float*)d_in[1];   // [U,T,N]
    const float* conn         = (const float*)d_in[2];   // [U,U]
    const float* target       = (const float*)d_in[3];   // [T,N]
    const float* rand_bias    = (const float*)d_in[4];   // [T,N]
    float* out = (float*)d_out;
    float* ws  = (float*)d_ws;

    unsigned int* ticket = (unsigned int*)(ws + 2 * NBLK);
    hipMemsetAsync(ticket, 0, sizeof(unsigned int), stream);   // graph-capturable memset node

    fused_kernel<<<NBLK, 256, 0, stream>>>(
        conn, (const vfloat4*)unit_outputs, (const vfloat4*)target,
        (const vfloat4*)input_spikes, (const vfloat4*)rand_bias,
        (vfloat4*)out, ws, ticket);
}

// Round 2
// 190.213 us; speedup vs baseline: 1.0633x; 1.0633x over previous
//
#include <hip/hip_runtime.h>

// Problem constants (fixed by setup_inputs)
#define U    128
#define TN   (256 * 1024)         // T*N output elements
#define TN4  (TN / 4)             // float4 granularity (65536)
#define NBLK 256                  // blocks in fused kernel (= TN4 / 256), 1 block/CU
#define PF   4                    // uo float4s prefetched before the w barrier (16 VGPRs)

// Native clang vector type — accepted by __builtin_nontemporal_load/store
typedef float vfloat4 __attribute__((ext_vector_type(4)));

// ws layout (floats): [0..255] per-block sum(final), [256..511] per-block sum(insp)
// Plain stores only — no zero-init needed on poisoned ws, no atomics.
// Cross-dispatch visibility is provided by the kernel boundary.
// NOTE (round-1 post-mortem): single-kernel last-block-ticket variant regressed
// +12 µs — device-scope __threadfence with ~1 MB dirty L2 across 8 non-coherent
// XCD L2s is expensive per-block. Two-dispatch structure is cheaper.

__global__ __launch_bounds__(256) void fused_kernel(const float*   __restrict__ conn,
                                                    const vfloat4* __restrict__ uo,
                                                    const vfloat4* __restrict__ tgt,
                                                    const vfloat4* __restrict__ insp,
                                                    vfloat4*       __restrict__ out,
                                                    float*         __restrict__ ws) {
    __shared__ float wpart[2][U];
    __shared__ float w_s[U];
    __shared__ float red[8];
    int tid = threadIdx.x;
    int idx = blockIdx.x * 256 + tid;            // 0..TN4-1

    // Early epilogue loads — overlap their latency with the w[] compute.
    vfloat4 t  = tgt[idx];
    vfloat4 is = insp[idx];

    // Start the 134 MB uo stream before the w barriers: 4 float4s in registers
    // (16 VGPRs — low pressure; round-1's PF=16 pinned 64 and regressed).
    const vfloat4* p = uo + idx;
    vfloat4 pre[PF];
#pragma unroll
    for (int k = 0; k < PF; ++k)
        pre[k] = __builtin_nontemporal_load(p + (size_t)k * TN4);

    // --- w[j] = 1.5 * sum_i gated(conn[i][j])  (3.0 strength × 0.5 epilogue folded)
    // Redundant per block, 64 KB from L2 — overlaps the in-flight loads above.
    {
        int j = tid & 127;
        int h = tid >> 7;
        const float* cp = conn + (size_t)(h * 64) * U + j;
        float s = 0.0f;
#pragma unroll
        for (int k = 0; k < 64; ++k) {
            float v = cp[(size_t)k * U];         // consecutive j -> coalesced
            s += (v > 0.1f) ? v : 0.0f;
        }
        wpart[h][j] = s;
    }
    __syncthreads();
    if (tid < U) w_s[tid] = 1.5f * (wpart[0][tid] + wpart[1][tid]);
    __syncthreads();

    // --- weighted j-reduction: consume prefetch, then one float4/thread,
    // 16 outstanding loads in steady state.
    vfloat4 acc = 0.0f;
#pragma unroll
    for (int k = 0; k < PF; ++k)
        acc += w_s[k] * pre[k];
#pragma unroll 16
    for (int jj = PF; jj < U; ++jj)
        acc += w_s[jj] * __builtin_nontemporal_load(p + (size_t)jj * TN4);

    vfloat4 r = acc + 1.5f * t;                  // 0.5*sum already folded into w_s
    __builtin_nontemporal_store(r, out + idx);   // written once; keep L2 clean

    // --- per-block partial sums: sum(final), sum(input_spikes)
    float lsum = r.x + r.y + r.z + r.w;
    float lin  = is.x + is.y + is.z + is.w;
#pragma unroll
    for (int off = 32; off > 0; off >>= 1) {
        lsum += __shfl_down(lsum, off, 64);
        lin  += __shfl_down(lin,  off, 64);
    }
    int wave = tid >> 6;
    int lane = tid & 63;
    if (lane == 0) { red[wave] = lsum; red[4 + wave] = lin; }
    __syncthreads();
    if (tid == 0) {
        ws[blockIdx.x]        = red[0] + red[1] + red[2] + red[3];
        ws[NBLK + blockIdx.x] = red[4] + red[5] + red[6] + red[7];
    }
}

// Boost: each block tree-reduces the 512 L2-hot partials, then conditionally
// applies. Branch is dead for this data (mean >> 0.2) so rb is never fetched.
__global__ __launch_bounds__(256) void boost_kernel(const vfloat4* __restrict__ rb,
                                                    vfloat4*       __restrict__ out,
                                                    const float*   __restrict__ ws) {
    int tid = threadIdx.x;
    float lsum = ws[tid];                        // 256 partials, one per thread
    float lin  = ws[NBLK + tid];
#pragma unroll
    for (int off = 32; off > 0; off >>= 1) {
        lsum += __shfl_down(lsum, off, 64);
        lin  += __shfl_down(lin,  off, 64);
    }
    __shared__ float red[8];
    int wave = tid >> 6;
    int lane = tid & 63;
    if (lane == 0) { red[wave] = lsum; red[4 + wave] = lin; }
    __syncthreads();
    float tot = red[0] + red[1] + red[2] + red[3];
    float tin = red[4] + red[5] + red[6] + red[7];

    float mean        = tot * (1.0f / TN);
    float in_rate     = tin * (1000.0f / TN);    // input_spikes.mean() * 1000
    float target_mean = (in_rate + 20.0f) * 0.01f;
    float boost       = fmaxf(0.0f, target_mean - mean);
    if (mean < 0.2f) {
        int idx = blockIdx.x * 256 + tid;
        out[idx] += rb[idx] * (boost * 2.0f);
    }
}

extern "C" void kernel_launch(void* const* d_in, const int* in_sizes, int n_in,
                              void* d_out, int out_size, void* d_ws, size_t ws_size,
                              hipStream_t stream) {
    const float* input_spikes = (const float*)d_in[0];   // [T,N]
    const float* unit_outputs = (const float*)d_in[1];   // [U,T,N]
    const float* conn         = (const float*)d_in[2];   // [U,U]
    const float* target       = (const float*)d_in[3];   // [T,N]
    const float* rand_bias    = (const float*)d_in[4];   // [T,N]
    float* out = (float*)d_out;
    float* ws  = (float*)d_ws;

    fused_kernel<<<NBLK, 256, 0, stream>>>(
        conn, (const vfloat4*)unit_outputs, (const vfloat4*)target,
        (const vfloat4*)input_spikes, (vfloat4*)out, ws);

    boost_kernel<<<TN4 / 256, 256, 0, stream>>>(
        (const vfloat4*)rand_bias, (vfloat4*)out, ws);
}